// Round 9
// baseline (1019.239 us; speedup 1.0000x reference)
//
#include <hip/hip_runtime.h>
#include <hip/hip_cooperative_groups.h>
#include <math.h>

namespace cg = cooperative_groups;

#define SE_B     32
#define SE_C     256
#define SE_R     16
#define SE_HW    16384                // floats per plane (128*128)
#define SE_NP    (SE_B * SE_C)        // 8192 planes
#define NBLK     1024                 // 4 blocks/CU (LDS-limited), coop-validated
#define NROUND   (SE_NP / NBLK)       // 8

typedef float v4f __attribute__((ext_vector_type(4)));
typedef unsigned int u32;
typedef u32 v4u __attribute__((ext_vector_type(4)));

// pack two fp32 -> one u32 of two bf16 (round-half-up); validated R7 (absmax .0156)
__device__ inline u32 pk(float a, float b) {
    u32 ua = __float_as_uint(a), ub = __float_as_uint(b);
    return ((ua + 0x8000u) >> 16) | ((ub + 0x8000u) & 0xffff0000u);
}

// ================= persistent pipelined kernel =================
// Each block, per round: load one plane (fp32, NT) -> fp32 sum + bf16 copy in
// LDS -> publish pooled[p] -> bump done[b] -> spin until batch complete ->
// block-local gate MLP -> scale bf16 plane from LDS -> NT store.
// x is read from HBM exactly once; out written once. 1.07 GB total.
__global__ __launch_bounds__(256) void se_pipe_kernel(
    const float* __restrict__ x,
    const float* __restrict__ w1,     // [R, C]
    const float* __restrict__ w2,     // [C, R]
    float* __restrict__ out,
    float* __restrict__ pooled,       // ws: [8192]
    int* __restrict__ done) {         // ws: [32], zeroed each call
    const int t = threadIdx.x;

    __shared__ u32   plane_lds[SE_HW / 2];       // 32 KiB, 8192 u32 (bf16 pairs)
    __shared__ float wsum[4];
    __shared__ float p_lds[SE_C];
    __shared__ float hpart[SE_R][SE_R + 1];
    __shared__ float h_lds[SE_R];
    __shared__ float g_lds;

    for (int r = 0; r < NROUND; ++r) {
        const int p = r * NBLK + blockIdx.x;
        const int b = p >> 8;                    // batch
        const int c = p & 255;                   // channel
        const v4f* xv = reinterpret_cast<const v4f*>(x) + (size_t)p * (SE_HW / 4);
        v4f*       ov = reinterpret_cast<v4f*>(out)     + (size_t)p * (SE_HW / 4);

        // ---- load plane once: fp32 sum + bf16 LDS copy ----
        float s = 0.f;
#pragma unroll
        for (int j = 0; j < 8; ++j) {
            v4f a = __builtin_nontemporal_load(&xv[(2 * j) * 256 + t]);
            v4f bb = __builtin_nontemporal_load(&xv[(2 * j + 1) * 256 + t]);
            s += (a.x + a.y) + (a.z + a.w) + (bb.x + bb.y) + (bb.z + bb.w);
            v4u pkd;
            pkd.x = pk(a.x, a.y);  pkd.y = pk(a.z, a.w);
            pkd.z = pk(bb.x, bb.y); pkd.w = pk(bb.z, bb.w);
            reinterpret_cast<v4u*>(plane_lds)[j * 256 + t] = pkd;
        }
#pragma unroll
        for (int off = 32; off > 0; off >>= 1) s += __shfl_down(s, off, 64);
        if ((t & 63) == 0) wsum[t >> 6] = s;
        __syncthreads();
        if (t == 0) {
            const float tot = (wsum[0] + wsum[1]) + (wsum[2] + wsum[3]);
            __hip_atomic_store(&pooled[p], tot * (1.0f / SE_HW),
                               __ATOMIC_RELAXED, __HIP_MEMORY_SCOPE_AGENT);
            __hip_atomic_fetch_add(&done[b], 1,
                                   __ATOMIC_RELEASE, __HIP_MEMORY_SCOPE_AGENT);
            // spin until all 256 planes of this batch are pooled
            while (__hip_atomic_load(&done[b], __ATOMIC_ACQUIRE,
                                     __HIP_MEMORY_SCOPE_AGENT) < SE_C)
                __builtin_amdgcn_s_sleep(8);
        }
        __syncthreads();

        // ---- gate for (b,c), block-cooperative MLP (validated R8) ----
        p_lds[t] = __hip_atomic_load(&pooled[b * SE_C + t],
                                     __ATOMIC_RELAXED, __HIP_MEMORY_SCOPE_AGENT);
        __syncthreads();
        {
            const int rr = t & 15, seg = t >> 4;
            float acc = 0.f;
#pragma unroll
            for (int j = 0; j < 16; ++j) {
                const int cc = seg * 16 + j;
                acc = fmaf(p_lds[cc], w1[rr * SE_C + cc], acc);
            }
            hpart[rr][seg] = acc;
        }
        __syncthreads();
        if (t < SE_R) {
            float acc = 0.f;
#pragma unroll
            for (int j = 0; j < 16; ++j) acc += hpart[t][j];
            h_lds[t] = fmaxf(acc, 0.f);
        }
        __syncthreads();
        if (t == 0) {
            float acc = 0.f;
#pragma unroll
            for (int rr = 0; rr < SE_R; ++rr)
                acc = fmaf(h_lds[rr], w2[c * SE_R + rr], acc);
            g_lds = 1.0f / (1.0f + expf(-acc));
        }
        __syncthreads();
        const float g = g_lds;

        // ---- scale from LDS bf16 copy, NT store ----
#pragma unroll
        for (int j = 0; j < 8; ++j) {
            v4u pkd = reinterpret_cast<const v4u*>(plane_lds)[j * 256 + t];
            v4f a, bb;
            a.x  = __uint_as_float(pkd.x << 16); a.y  = __uint_as_float(pkd.x & 0xffff0000u);
            a.z  = __uint_as_float(pkd.y << 16); a.w  = __uint_as_float(pkd.y & 0xffff0000u);
            bb.x = __uint_as_float(pkd.z << 16); bb.y = __uint_as_float(pkd.z & 0xffff0000u);
            bb.z = __uint_as_float(pkd.w << 16); bb.w = __uint_as_float(pkd.w & 0xffff0000u);
            a *= g; bb *= g;
            __builtin_nontemporal_store(a,  &ov[(2 * j) * 256 + t]);
            __builtin_nontemporal_store(bb, &ov[(2 * j + 1) * 256 + t]);
        }
        __syncthreads();                          // protect LDS before next round
    }
}

// ================= fallback: proven 252 us bf16 3-kernel path =================
__global__ __launch_bounds__(256) void se_pool_pack(const float* __restrict__ x,
                                                    u32* __restrict__ xh,
                                                    float* __restrict__ pooled) {
    const int plane = blockIdx.x;
    const int t = threadIdx.x;
    const v4f* xv = reinterpret_cast<const v4f*>(x) + (size_t)plane * (SE_HW / 4);
    v4u* xh4 = reinterpret_cast<v4u*>(xh) + (size_t)plane * (SE_HW / 8);
    float s = 0.f;
#pragma unroll
    for (int j = 0; j < 8; ++j) {
        v4f a = __builtin_nontemporal_load(&xv[(2 * j) * 256 + t]);
        v4f b = __builtin_nontemporal_load(&xv[(2 * j + 1) * 256 + t]);
        s += (a.x + a.y) + (a.z + a.w) + (b.x + b.y) + (b.z + b.w);
        v4u p;
        p.x = pk(a.x, a.y); p.y = pk(a.z, a.w);
        p.z = pk(b.x, b.y); p.w = pk(b.z, b.w);
        xh4[j * 256 + t] = p;
    }
#pragma unroll
    for (int off = 32; off > 0; off >>= 1) s += __shfl_down(s, off, 64);
    __shared__ float ws[4];
    if ((t & 63) == 0) ws[t >> 6] = s;
    __syncthreads();
    if (t == 0) pooled[plane] = ((ws[0] + ws[1]) + (ws[2] + ws[3])) * (1.0f / SE_HW);
}

__global__ __launch_bounds__(256) void se_gate_kernel(const float* __restrict__ pooled,
                                                      const float* __restrict__ w1,
                                                      const float* __restrict__ w2,
                                                      float* __restrict__ gate) {
    const int b = blockIdx.x;
    const int t = threadIdx.x;
    __shared__ float p[SE_C];
    __shared__ float h[SE_R];
    p[t] = pooled[b * SE_C + t];
    __syncthreads();
    if (t < SE_R) {
        float acc = 0.f;
        for (int c = 0; c < SE_C; ++c) acc = fmaf(p[c], w1[t * SE_C + c], acc);
        h[t] = fmaxf(acc, 0.f);
    }
    __syncthreads();
    float acc = 0.f;
#pragma unroll
    for (int r = 0; r < SE_R; ++r) acc = fmaf(h[r], w2[t * SE_R + r], acc);
    gate[b * SE_C + t] = 1.0f / (1.0f + expf(-acc));
}

__global__ __launch_bounds__(256) void se_scale_bf16(const u32* __restrict__ xh,
                                                     const float* __restrict__ gate,
                                                     float* __restrict__ out) {
    const int plane = SE_NP - 1 - blockIdx.x;
    const int t = threadIdx.x;
    const float g = gate[plane];
    const v4u* xh4 = reinterpret_cast<const v4u*>(xh) + (size_t)plane * (SE_HW / 8);
    v4f* ov = reinterpret_cast<v4f*>(out) + (size_t)plane * (SE_HW / 4);
#pragma unroll
    for (int j = 0; j < 8; ++j) {
        v4u p = xh4[j * 256 + t];
        v4f a, b;
        a.x = __uint_as_float(p.x << 16);  a.y = __uint_as_float(p.x & 0xffff0000u);
        a.z = __uint_as_float(p.y << 16);  a.w = __uint_as_float(p.y & 0xffff0000u);
        b.x = __uint_as_float(p.z << 16);  b.y = __uint_as_float(p.z & 0xffff0000u);
        b.z = __uint_as_float(p.w << 16);  b.w = __uint_as_float(p.w & 0xffff0000u);
        a *= g; b *= g;
        __builtin_nontemporal_store(a, &ov[(2 * j) * 256 + t]);
        __builtin_nontemporal_store(b, &ov[(2 * j + 1) * 256 + t]);
    }
}

extern "C" void kernel_launch(void* const* d_in, const int* in_sizes, int n_in,
                              void* d_out, int out_size, void* d_ws, size_t ws_size,
                              hipStream_t stream) {
    const float* x  = (const float*)d_in[0];   // [32,256,128,128]
    const float* w1 = (const float*)d_in[1];   // [16,256]
    const float* w2 = (const float*)d_in[2];   // [256,16]
    float* out = (float*)d_out;

    float* pooled  = (float*)d_ws;                                    // 32 KiB
    int*   done    = (int*)((char*)d_ws + SE_NP * sizeof(float));     // 128 B
    float* gatebuf = (float*)((char*)d_ws + SE_NP * sizeof(float) + 256);
    u32*   xh      = (u32*)((char*)d_ws + 2 * SE_NP * sizeof(float) + 256);

    hipMemsetAsync(done, 0, SE_B * sizeof(int), stream);   // counters start at 0

    void* args[] = { (void*)&x, (void*)&w1, (void*)&w2, (void*)&out,
                     (void*)&pooled, (void*)&done };
    hipError_t err = hipLaunchCooperativeKernel((void*)se_pipe_kernel,
                                                dim3(NBLK), dim3(256),
                                                args, 0, stream);
    if (err != hipSuccess) {
        (void)hipGetLastError();               // clear sticky error; proven path
        se_pool_pack<<<SE_NP, 256, 0, stream>>>(x, xh, pooled);
        se_gate_kernel<<<SE_B, 256, 0, stream>>>(pooled, w1, w2, gatebuf);
        se_scale_bf16<<<SE_NP, 256, 0, stream>>>(xh, gatebuf, out);
    }
}

// Round 10
// 284.846 us; speedup vs baseline: 3.5782x; 3.5782x over previous
//
#include <hip/hip_runtime.h>
#include <math.h>

#define SE_B     32
#define SE_C     256
#define SE_R     16
#define SE_HW    16384                 // floats per plane (128*128)
#define SE_NP    (SE_B * SE_C)         // 8192 planes
#define CHUNK_B  4                     // batches per chunk: 64MB x + 67MB out = 131MB < 256MB MALL
#define CHUNK_P  (CHUNK_B * SE_C)      // 1024 planes per chunk
#define NCHUNK   (SE_B / CHUNK_B)      // 8 chunks

typedef float v4f __attribute__((ext_vector_type(4)));

// ---- K1: pool one chunk. One block per plane; PLAIN loads so x allocates
// in the memory-side L3 (MALL) for the scale pass to re-read. ----
__global__ __launch_bounds__(256) void se_pool_chunk(const float* __restrict__ x,
                                                     float* __restrict__ pooled,
                                                     int base_plane) {
    const int plane = base_plane + blockIdx.x;
    const int t = threadIdx.x;
    const v4f* xv = reinterpret_cast<const v4f*>(x) + (size_t)plane * (SE_HW / 4);
    float s = 0.f;
#pragma unroll
    for (int k = 0; k < 16; ++k) {
        v4f v = xv[k * 256 + t];
        s += (v.x + v.y) + (v.z + v.w);
    }
#pragma unroll
    for (int off = 32; off > 0; off >>= 1) s += __shfl_down(s, off, 64);
    __shared__ float ws[4];
    if ((t & 63) == 0) ws[t >> 6] = s;
    __syncthreads();
    if (t == 0) pooled[plane] = ((ws[0] + ws[1]) + (ws[2] + ws[3])) * (1.0f / SE_HW);
}

// ---- K2: fused gate + scale for one chunk. One block per plane.
// Block redundantly computes its own gate value (tiny MLP, ~1us), then
// scales its plane: x reads should hit MALL (written by K1 of this chunk,
// 131MB in-flight < 256MB), out NT-stored. ----
__global__ __launch_bounds__(256) void se_scale_chunk(const float* __restrict__ x,
                                                      const float* __restrict__ pooled,
                                                      const float* __restrict__ w1,   // [R,C]
                                                      const float* __restrict__ w2,   // [C,R]
                                                      float* __restrict__ out,
                                                      int base_plane) {
    const int plane = base_plane + blockIdx.x;
    const int b = plane >> 8;                 // plane / 256
    const int c = plane & 255;                // plane % 256
    const int t = threadIdx.x;

    __shared__ float p_lds[SE_C];
    __shared__ float hpart[SE_R][SE_R + 1];
    __shared__ float h_lds[SE_R];
    __shared__ float g_lds;

    p_lds[t] = pooled[b * SE_C + t];
    __syncthreads();
    {   // h[r] = relu(sum_c p[c]*w1[r,c]); C split into 16 segments
        const int r = t & 15, seg = t >> 4;
        float acc = 0.f;
#pragma unroll
        for (int j = 0; j < 16; ++j) {
            const int cc = seg * 16 + j;
            acc = fmaf(p_lds[cc], w1[r * SE_C + cc], acc);
        }
        hpart[r][seg] = acc;
    }
    __syncthreads();
    if (t < SE_R) {
        float acc = 0.f;
#pragma unroll
        for (int j = 0; j < 16; ++j) acc += hpart[t][j];
        h_lds[t] = fmaxf(acc, 0.f);
    }
    __syncthreads();
    if (t == 0) {
        float acc = 0.f;
#pragma unroll
        for (int r = 0; r < SE_R; ++r) acc = fmaf(h_lds[r], w2[c * SE_R + r], acc);
        g_lds = 1.0f / (1.0f + expf(-acc));
    }
    __syncthreads();
    const float g = g_lds;

    // scale the plane: MALL-hit reads (hopefully), NT stores
    const v4f* xv = reinterpret_cast<const v4f*>(x) + (size_t)plane * (SE_HW / 4);
    v4f* ov = reinterpret_cast<v4f*>(out) + (size_t)plane * (SE_HW / 4);
#pragma unroll
    for (int k = 0; k < 16; ++k) {
        v4f v = xv[k * 256 + t];
        v *= g;
        __builtin_nontemporal_store(v, &ov[k * 256 + t]);
    }
}

extern "C" void kernel_launch(void* const* d_in, const int* in_sizes, int n_in,
                              void* d_out, int out_size, void* d_ws, size_t ws_size,
                              hipStream_t stream) {
    const float* x  = (const float*)d_in[0];   // [32,256,128,128]
    const float* w1 = (const float*)d_in[1];   // [16,256]
    const float* w2 = (const float*)d_in[2];   // [256,16]
    float* out = (float*)d_out;
    float* pooled = (float*)d_ws;              // 8192 floats = 32 KiB

    for (int ch = 0; ch < NCHUNK; ++ch) {
        const int base = ch * CHUNK_P;
        se_pool_chunk<<<CHUNK_P, 256, 0, stream>>>(x, pooled, base);
        se_scale_chunk<<<CHUNK_P, 256, 0, stream>>>(x, pooled, w1, w2, out, base);
    }
}